// Round 1
// baseline (1951.237 us; speedup 1.0000x reference)
//
#include <hip/hip_runtime.h>
#include <hip/hip_bf16.h>
#include <stdint.h>

#define BB 8
#define NN 2048
#define DD 64
#define REGv 0.1f
#define NUM_ITERS 50
#define EPS_NORM 1e-8f
#define EPS_SINK 1e-10f
#define CHUNK 8
#define NBLK (NN / CHUNK)   // 256

// ---------------- init: v = 1/N, maxd = 0 ----------------
__global__ void init_k(float* v, unsigned* maxd) {
    int t = blockIdx.x * 256 + threadIdx.x;
    if (t < BB * NN) v[t] = 1.0f / (float)NN;
    if (t < BB) maxd[t] = 0u;
}

// ---------------- row squared norms (one wave per row) ----------------
__global__ void sq_k(const float* __restrict__ x0, const float* __restrict__ x1,
                     float* __restrict__ sq0, float* __restrict__ sq1) {
    int w = (blockIdx.x * 256 + threadIdx.x) >> 6;   // wave id = row id
    int lane = threadIdx.x & 63;
    if (w >= 2 * BB * NN) return;
    const float* src = (w < BB * NN) ? x0 : x1;
    int r = (w < BB * NN) ? w : w - BB * NN;
    float val = src[(size_t)r * DD + lane];
    float s = val * val;
    #pragma unroll
    for (int off = 32; off; off >>= 1) s += __shfl_xor(s, off);
    if (lane == 0) ((w < BB * NN) ? sq0 : sq1)[r] = s;
}

// ---------------- cdist tile kernel: d into Kd, per-batch max ----------------
#define PAD 68
__global__ __launch_bounds__(256) void dist_k(const float* __restrict__ x0,
                                              const float* __restrict__ x1,
                                              const float* __restrict__ sq0,
                                              const float* __restrict__ sq1,
                                              float* __restrict__ Kd,
                                              unsigned* __restrict__ maxd) {
    __shared__ float x0s[64 * PAD];
    __shared__ float x1s[64 * PAD];
    __shared__ float wmax[4];
    int bid = blockIdx.x;
    int b = bid >> 10;            // 32*32 tiles per batch
    int tile = bid & 1023;
    int ti = tile >> 5, tj = tile & 31;
    int i0 = ti * 64, j0 = tj * 64;
    int t = threadIdx.x;

    const float4* g0 = (const float4*)(x0 + ((size_t)b * NN + i0) * DD);
    const float4* g1 = (const float4*)(x1 + ((size_t)b * NN + j0) * DD);
    #pragma unroll
    for (int rep = 0; rep < 4; rep++) {
        int e = rep * 256 + t;          // 0..1023 covers 64 rows x 16 float4
        int row = e >> 4, c4 = e & 15;
        float4 a = g0[row * 16 + c4];
        x0s[row * PAD + c4 * 4 + 0] = a.x; x0s[row * PAD + c4 * 4 + 1] = a.y;
        x0s[row * PAD + c4 * 4 + 2] = a.z; x0s[row * PAD + c4 * 4 + 3] = a.w;
        float4 c = g1[row * 16 + c4];
        x1s[row * PAD + c4 * 4 + 0] = c.x; x1s[row * PAD + c4 * 4 + 1] = c.y;
        x1s[row * PAD + c4 * 4 + 2] = c.z; x1s[row * PAD + c4 * 4 + 3] = c.w;
    }
    __syncthreads();

    int tx = t & 15, tyb = t >> 4;       // output: i = tyb*4+di, j = tx + 16*dj
    float acc[4][4];
    #pragma unroll
    for (int a = 0; a < 4; a++)
        #pragma unroll
        for (int c = 0; c < 4; c++) acc[a][c] = 0.0f;

    #pragma unroll
    for (int k4 = 0; k4 < 16; k4++) {
        float4 av[4], bv[4];
        #pragma unroll
        for (int di = 0; di < 4; di++)
            av[di] = *(const float4*)&x0s[(tyb * 4 + di) * PAD + k4 * 4];
        #pragma unroll
        for (int dj = 0; dj < 4; dj++)
            bv[dj] = *(const float4*)&x1s[(tx + 16 * dj) * PAD + k4 * 4];
        #pragma unroll
        for (int di = 0; di < 4; di++)
            #pragma unroll
            for (int dj = 0; dj < 4; dj++)
                acc[di][dj] += av[di].x * bv[dj].x + av[di].y * bv[dj].y +
                               av[di].z * bv[dj].z + av[di].w * bv[dj].w;
    }

    float lmax = 0.0f;
    #pragma unroll
    for (int di = 0; di < 4; di++) {
        float s0 = sq0[(size_t)b * NN + i0 + tyb * 4 + di];
        #pragma unroll
        for (int dj = 0; dj < 4; dj++) {
            float s1 = sq1[(size_t)b * NN + j0 + tx + 16 * dj];
            float d2 = s0 + s1 - 2.0f * acc[di][dj];
            float d = sqrtf(fmaxf(d2, 0.0f));
            lmax = fmaxf(lmax, d);
            Kd[((size_t)b * NN + i0 + tyb * 4 + di) * NN + j0 + tx + 16 * dj] = d;
        }
    }
    #pragma unroll
    for (int off = 32; off; off >>= 1) lmax = fmaxf(lmax, __shfl_xor(lmax, off));
    if ((t & 63) == 0) wmax[t >> 6] = lmax;
    __syncthreads();
    if (t == 0) {
        float m = fmaxf(fmaxf(wmax[0], wmax[1]), fmaxf(wmax[2], wmax[3]));
        atomicMax(&maxd[b], __float_as_uint(m));   // d>=0: uint compare == float compare
    }
}

// ---------------- K = exp(-(d/(max+eps))/REG) elementwise ----------------
__global__ void expk_k(float* __restrict__ Kd, const unsigned* __restrict__ maxd) {
    size_t total4 = (size_t)BB * NN * NN / 4;
    for (size_t i4 = (size_t)blockIdx.x * 256 + threadIdx.x; i4 < total4;
         i4 += (size_t)gridDim.x * 256) {
        int b = (int)(i4 >> 20);     // N*N/4 = 2^20
        float mv = __uint_as_float(maxd[b]) + EPS_NORM;
        float4 d4 = ((float4*)Kd)[i4];
        d4.x = expf(-((d4.x / mv) / REGv));
        d4.y = expf(-((d4.y / mv) / REGv));
        d4.z = expf(-((d4.z / mv) / REGv));
        d4.w = expf(-((d4.w / mv) / REGv));
        ((float4*)Kd)[i4] = d4;
    }
}

// ---------------- fused Sinkhorn: u for 8 rows + column partials ----------------
__global__ __launch_bounds__(256) void sink_k(const float* __restrict__ Kd,
                                              const float* __restrict__ v,
                                              float* __restrict__ u,
                                              float* __restrict__ partial) {
    __shared__ float red[4][CHUNK];
    int bid = blockIdx.x;
    int b = bid >> 8;                 // NBLK=256 blocks per batch
    int chunk = bid & 255;
    int row0 = chunk * CHUNK;
    int t = threadIdx.x;

    const float4* v4 = (const float4*)(v + (size_t)b * NN);
    float4 vA = v4[t], vB = v4[t + 256];

    const float4* Krow = (const float4*)(Kd + ((size_t)b * NN + row0) * NN);
    float4 kA[CHUNK], kB[CHUNK];
    #pragma unroll
    for (int r = 0; r < CHUNK; r++) {
        kA[r] = Krow[r * 512 + t];
        kB[r] = Krow[r * 512 + 256 + t];
    }

    // phase 1: row dot products -> u
    float dp[CHUNK];
    #pragma unroll
    for (int r = 0; r < CHUNK; r++)
        dp[r] = kA[r].x * vA.x + kA[r].y * vA.y + kA[r].z * vA.z + kA[r].w * vA.w +
                kB[r].x * vB.x + kB[r].y * vB.y + kB[r].z * vB.z + kB[r].w * vB.w;
    #pragma unroll
    for (int r = 0; r < CHUNK; r++)
        #pragma unroll
        for (int off = 32; off; off >>= 1) dp[r] += __shfl_xor(dp[r], off);
    int lane = t & 63, w = t >> 6;
    if (lane == 0) {
        #pragma unroll
        for (int r = 0; r < CHUNK; r++) red[w][r] = dp[r];
    }
    __syncthreads();
    float uu[CHUNK];
    #pragma unroll
    for (int r = 0; r < CHUNK; r++)
        uu[r] = 1.0f / (red[0][r] + red[1][r] + red[2][r] + red[3][r] + EPS_SINK);
    if (t < CHUNK)
        u[(size_t)b * NN + row0 + t] =
            1.0f / (red[0][t] + red[1][t] + red[2][t] + red[3][t] + EPS_SINK);

    // phase 2: column partials with the fresh u's (K still in registers)
    float4 accA = {0, 0, 0, 0}, accB = {0, 0, 0, 0};
    #pragma unroll
    for (int r = 0; r < CHUNK; r++) {
        accA.x += uu[r] * kA[r].x; accA.y += uu[r] * kA[r].y;
        accA.z += uu[r] * kA[r].z; accA.w += uu[r] * kA[r].w;
        accB.x += uu[r] * kB[r].x; accB.y += uu[r] * kB[r].y;
        accB.z += uu[r] * kB[r].z; accB.w += uu[r] * kB[r].w;
    }
    float4* p4 = (float4*)(partial + ((size_t)b * NBLK + chunk) * NN);
    p4[t] = accA;
    p4[t + 256] = accB;
}

// ---------------- v = 1/(sum partials + eps) ----------------
__global__ void vred_k(const float* __restrict__ partial, float* __restrict__ v) {
    int j = blockIdx.x * 256 + threadIdx.x;     // 0..B*N
    int b = j >> 11, jj = j & 2047;
    const float* p = partial + (size_t)b * NBLK * NN + jj;
    float s = 0.0f;
    for (int c = 0; c < NBLK; c++) s += p[(size_t)c * NN];
    v[j] = 1.0f / (s + EPS_SINK);
}

// ---------------- argmax over columns of P = (u*K)*v ----------------
__global__ __launch_bounds__(256) void argmax_k(const float* __restrict__ Kd,
                                                const float* __restrict__ u,
                                                const float* __restrict__ v,
                                                int* __restrict__ out) {
    int w = (blockIdx.x * 256 + threadIdx.x) >> 6;   // wave per row
    int lane = threadIdx.x & 63;
    int b = w >> 11, i = w & 2047;
    float uu = u[(size_t)b * NN + i];
    const float4* Kr = (const float4*)(Kd + ((size_t)b * NN + i) * NN);
    const float4* v4 = (const float4*)(v + (size_t)b * NN);
    float best = -1.0f;
    int bidx = 0;
    for (int it = 0; it < 8; it++) {
        int c4 = it * 64 + lane;
        float4 kk = Kr[c4];
        float4 vv = v4[c4];
        int j = c4 * 4;
        float p0 = (uu * kk.x) * vv.x;
        float p1 = (uu * kk.y) * vv.y;
        float p2 = (uu * kk.z) * vv.z;
        float p3 = (uu * kk.w) * vv.w;
        if (p0 > best) { best = p0; bidx = j; }
        if (p1 > best) { best = p1; bidx = j + 1; }
        if (p2 > best) { best = p2; bidx = j + 2; }
        if (p3 > best) { best = p3; bidx = j + 3; }
    }
    #pragma unroll
    for (int off = 32; off; off >>= 1) {
        float ov = __shfl_xor(best, off);
        int oi = __shfl_xor(bidx, off);
        if (ov > best || (ov == best && oi < bidx)) { best = ov; bidx = oi; }
    }
    if (lane == 0) out[(size_t)b * NN + i] = bidx;
}

extern "C" void kernel_launch(void* const* d_in, const int* in_sizes, int n_in,
                              void* d_out, int out_size, void* d_ws, size_t ws_size,
                              hipStream_t stream) {
    const float* x0 = (const float*)d_in[0];
    const float* x1 = (const float*)d_in[1];
    int* out = (int*)d_out;
    char* ws = (char*)d_ws;

    // ws layout (bytes)
    float* Kd      = (float*)(ws + 0ull);                 // 134217728
    float* partial = (float*)(ws + 134217728ull);         // 16777216
    float* u       = (float*)(ws + 150994944ull);         // 65536
    float* v       = (float*)(ws + 151060480ull);         // 65536
    float* sq0     = (float*)(ws + 151126016ull);         // 65536
    float* sq1     = (float*)(ws + 151191552ull);         // 65536
    unsigned* maxd = (unsigned*)(ws + 151257088ull);      // 32

    init_k<<<64, 256, 0, stream>>>(v, maxd);
    sq_k<<<8192, 256, 0, stream>>>(x0, x1, sq0, sq1);
    dist_k<<<8192, 256, 0, stream>>>(x0, x1, sq0, sq1, Kd, maxd);
    expk_k<<<2048, 256, 0, stream>>>(Kd, maxd);
    for (int it = 0; it < NUM_ITERS; ++it) {
        sink_k<<<2048, 256, 0, stream>>>(Kd, v, u, partial);
        vred_k<<<64, 256, 0, stream>>>(partial, v);
    }
    argmax_k<<<4096, 256, 0, stream>>>(Kd, u, v, out);
}

// Round 2
// 1660.893 us; speedup vs baseline: 1.1748x; 1.1748x over previous
//
#include <hip/hip_runtime.h>
#include <hip/hip_bf16.h>
#include <stdint.h>

#define BB 8
#define NN 2048
#define DD 64
#define REGv 0.1f
#define NUM_ITERS 50
#define EPS_NORM 1e-8f
#define EPS_SINK 1e-10f
#define CHUNK 16
#define NBLK (NN / CHUNK)   // 128

// ---------------- init: v = 1/N, maxd2 = 0 ----------------
__global__ void init_k(float* v, unsigned* maxd) {
    int t = blockIdx.x * 256 + threadIdx.x;
    if (t < BB * NN) v[t] = 1.0f / (float)NN;
    if (t < BB) maxd[t] = 0u;
}

// ---------------- row squared norms (one wave per row) ----------------
__global__ void sq_k(const float* __restrict__ x0, const float* __restrict__ x1,
                     float* __restrict__ sq0, float* __restrict__ sq1) {
    int w = (blockIdx.x * 256 + threadIdx.x) >> 6;   // wave id = row id
    int lane = threadIdx.x & 63;
    if (w >= 2 * BB * NN) return;
    const float* src = (w < BB * NN) ? x0 : x1;
    int r = (w < BB * NN) ? w : w - BB * NN;
    float val = src[(size_t)r * DD + lane];
    float s = val * val;
    #pragma unroll
    for (int off = 32; off; off >>= 1) s += __shfl_xor(s, off);
    if (lane == 0) ((w < BB * NN) ? sq0 : sq1)[r] = s;
}

// ---------------- fused cdist: WRITE=0 -> d2 max only; WRITE=1 -> K=exp ----------------
// tile: 128 (i) x 64 (j), block 256 = 16tx x 16ty, per-thread 8x4 outputs
template<int WRITE>
__global__ __launch_bounds__(256) void distc_k(const float* __restrict__ x0,
                                               const float* __restrict__ x1,
                                               const float* __restrict__ sq0,
                                               const float* __restrict__ sq1,
                                               float* __restrict__ Kd,
                                               unsigned* __restrict__ maxd) {
    __shared__ float x0s[128 * 68];   // [i][k] row-major, pad 68
    __shared__ float x1t[64 * 68];    // [k][j] transposed, pad 68
    __shared__ float wred[4];
    int bid = blockIdx.x;
    int b = bid >> 9;                 // 16*32 = 512 tiles per batch
    int tile = bid & 511;
    int ti = tile >> 5, tj = tile & 31;
    int i0 = ti * 128, j0 = tj * 64;
    int t = threadIdx.x;

    const float4* g0 = (const float4*)(x0 + ((size_t)b * NN + i0) * DD);
    #pragma unroll
    for (int rep = 0; rep < 8; rep++) {
        int e = rep * 256 + t;            // 2048 float4 = 128 rows x 16
        int row = e >> 4, c4 = e & 15;
        *(float4*)&x0s[row * 68 + c4 * 4] = g0[row * 16 + c4];
    }
    const float4* g1 = (const float4*)(x1 + ((size_t)b * NN + j0) * DD);
    #pragma unroll
    for (int rep = 0; rep < 4; rep++) {
        int e = rep * 256 + t;            // 1024 float4 = 64 rows x 16
        int row = e >> 4, c4 = e & 15;    // row = j, c4 = k quad
        float4 a = g1[row * 16 + c4];
        x1t[(c4 * 4 + 0) * 68 + row] = a.x;
        x1t[(c4 * 4 + 1) * 68 + row] = a.y;
        x1t[(c4 * 4 + 2) * 68 + row] = a.z;
        x1t[(c4 * 4 + 3) * 68 + row] = a.w;
    }
    __syncthreads();

    int tx = t & 15, ty = t >> 4;         // i = ty*8+di, j = tx*4+dj
    float4 acc4[8];
    #pragma unroll
    for (int di = 0; di < 8; di++) acc4[di] = make_float4(0.f, 0.f, 0.f, 0.f);

    #pragma unroll
    for (int k4 = 0; k4 < 16; k4++) {
        float4 b0 = *(const float4*)&x1t[(k4 * 4 + 0) * 68 + tx * 4];
        float4 b1 = *(const float4*)&x1t[(k4 * 4 + 1) * 68 + tx * 4];
        float4 b2 = *(const float4*)&x1t[(k4 * 4 + 2) * 68 + tx * 4];
        float4 b3 = *(const float4*)&x1t[(k4 * 4 + 3) * 68 + tx * 4];
        #pragma unroll
        for (int di = 0; di < 8; di++) {
            float4 a = *(const float4*)&x0s[(ty * 8 + di) * 68 + k4 * 4];
            acc4[di].x += a.x * b0.x + a.y * b1.x + a.z * b2.x + a.w * b3.x;
            acc4[di].y += a.x * b0.y + a.y * b1.y + a.z * b2.y + a.w * b3.y;
            acc4[di].z += a.x * b0.z + a.y * b1.z + a.z * b2.z + a.w * b3.z;
            acc4[di].w += a.x * b0.w + a.y * b1.w + a.z * b2.w + a.w * b3.w;
        }
    }

    int ib = b * NN + i0 + ty * 8;
    float4 s1 = *(const float4*)&sq1[b * NN + j0 + tx * 4];

    if (WRITE) {
        float mv = sqrtf(__uint_as_float(maxd[b])) + EPS_NORM;
        #pragma unroll
        for (int di = 0; di < 8; di++) {
            float s0 = sq0[ib + di];
            float4 o;
            o.x = expf(-((sqrtf(fmaxf(s0 + s1.x - 2.f * acc4[di].x, 0.f)) / mv) / REGv));
            o.y = expf(-((sqrtf(fmaxf(s0 + s1.y - 2.f * acc4[di].y, 0.f)) / mv) / REGv));
            o.z = expf(-((sqrtf(fmaxf(s0 + s1.z - 2.f * acc4[di].z, 0.f)) / mv) / REGv));
            o.w = expf(-((sqrtf(fmaxf(s0 + s1.w - 2.f * acc4[di].w, 0.f)) / mv) / REGv));
            *(float4*)&Kd[(size_t)(ib + di) * NN + j0 + tx * 4] = o;
        }
    } else {
        float lm = 0.0f;
        #pragma unroll
        for (int di = 0; di < 8; di++) {
            float s0 = sq0[ib + di];
            lm = fmaxf(lm, fmaxf(s0 + s1.x - 2.f * acc4[di].x, 0.f));
            lm = fmaxf(lm, fmaxf(s0 + s1.y - 2.f * acc4[di].y, 0.f));
            lm = fmaxf(lm, fmaxf(s0 + s1.z - 2.f * acc4[di].z, 0.f));
            lm = fmaxf(lm, fmaxf(s0 + s1.w - 2.f * acc4[di].w, 0.f));
        }
        #pragma unroll
        for (int off = 32; off; off >>= 1) lm = fmaxf(lm, __shfl_xor(lm, off));
        if ((t & 63) == 0) wred[t >> 6] = lm;
        __syncthreads();
        if (t == 0) {
            float m = fmaxf(fmaxf(wred[0], wred[1]), fmaxf(wred[2], wred[3]));
            atomicMax(&maxd[b], __float_as_uint(m));  // d2 >= 0: uint cmp == float cmp
        }
    }
}

// ---------------- fused Sinkhorn: u for 16 rows + column partials ----------------
__global__ __launch_bounds__(512) void sink_k(const float* __restrict__ Kd,
                                              const float* __restrict__ v,
                                              float* __restrict__ u,
                                              float* __restrict__ partial) {
    __shared__ float red[8][CHUNK];
    __shared__ float uu_s[CHUNK];
    int bid = blockIdx.x;
    int b = bid >> 7;                 // NBLK=128 blocks per batch
    int chunk = bid & 127;
    int row0 = chunk * CHUNK;
    int t = threadIdx.x;

    float4 vv = ((const float4*)(v + (size_t)b * NN))[t];
    const float4* Kr = (const float4*)(Kd + ((size_t)b * NN + row0) * NN);
    float4 kk[CHUNK];
    #pragma unroll
    for (int r = 0; r < CHUNK; r++) kk[r] = Kr[r * 512 + t];

    // phase 1: row dot products -> u
    float dp[CHUNK];
    #pragma unroll
    for (int r = 0; r < CHUNK; r++)
        dp[r] = kk[r].x * vv.x + kk[r].y * vv.y + kk[r].z * vv.z + kk[r].w * vv.w;
    #pragma unroll
    for (int r = 0; r < CHUNK; r++)
        #pragma unroll
        for (int off = 32; off; off >>= 1) dp[r] += __shfl_xor(dp[r], off);
    int lane = t & 63, w = t >> 6;
    if (lane == 0) {
        #pragma unroll
        for (int r = 0; r < CHUNK; r++) red[w][r] = dp[r];
    }
    __syncthreads();
    if (t < CHUNK) {
        float s = 0.0f;
        #pragma unroll
        for (int c = 0; c < 8; c++) s += red[c][t];
        float uu = 1.0f / (s + EPS_SINK);
        uu_s[t] = uu;
        u[(size_t)b * NN + row0 + t] = uu;
    }
    __syncthreads();

    // phase 2: column partials with fresh u (K still in registers)
    float4 acc = make_float4(0.f, 0.f, 0.f, 0.f);
    #pragma unroll
    for (int r = 0; r < CHUNK; r++) {
        float uur = uu_s[r];
        acc.x += uur * kk[r].x; acc.y += uur * kk[r].y;
        acc.z += uur * kk[r].z; acc.w += uur * kk[r].w;
    }
    ((float4*)(partial + ((size_t)b * NBLK + chunk) * NN))[t] = acc;
}

// ---------------- v = 1/(sum partials + eps) ----------------
__global__ void vred_k(const float* __restrict__ partial, float* __restrict__ v) {
    int j = blockIdx.x * 256 + threadIdx.x;     // 0..B*N
    int b = j >> 11, jj = j & 2047;
    const float* p = partial + (size_t)b * NBLK * NN + jj;
    float s = 0.0f;
    for (int c = 0; c < NBLK; c++) s += p[(size_t)c * NN];
    v[j] = 1.0f / (s + EPS_SINK);
}

// ---------------- argmax over columns of P = (u*K)*v ----------------
__global__ __launch_bounds__(256) void argmax_k(const float* __restrict__ Kd,
                                                const float* __restrict__ u,
                                                const float* __restrict__ v,
                                                int* __restrict__ out) {
    int w = (blockIdx.x * 256 + threadIdx.x) >> 6;   // wave per row
    int lane = threadIdx.x & 63;
    int b = w >> 11, i = w & 2047;
    float uu = u[(size_t)b * NN + i];
    const float4* Kr = (const float4*)(Kd + ((size_t)b * NN + i) * NN);
    const float4* v4 = (const float4*)(v + (size_t)b * NN);
    float best = -1.0f;
    int bidx = 0;
    for (int it = 0; it < 8; it++) {
        int c4 = it * 64 + lane;
        float4 kk = Kr[c4];
        float4 vv = v4[c4];
        int j = c4 * 4;
        float p0 = (uu * kk.x) * vv.x;
        float p1 = (uu * kk.y) * vv.y;
        float p2 = (uu * kk.z) * vv.z;
        float p3 = (uu * kk.w) * vv.w;
        if (p0 > best) { best = p0; bidx = j; }
        if (p1 > best) { best = p1; bidx = j + 1; }
        if (p2 > best) { best = p2; bidx = j + 2; }
        if (p3 > best) { best = p3; bidx = j + 3; }
    }
    #pragma unroll
    for (int off = 32; off; off >>= 1) {
        float ov = __shfl_xor(best, off);
        int oi = __shfl_xor(bidx, off);
        if (ov > best || (ov == best && oi < bidx)) { best = ov; bidx = oi; }
    }
    if (lane == 0) out[(size_t)b * NN + i] = bidx;
}

extern "C" void kernel_launch(void* const* d_in, const int* in_sizes, int n_in,
                              void* d_out, int out_size, void* d_ws, size_t ws_size,
                              hipStream_t stream) {
    const float* x0 = (const float*)d_in[0];
    const float* x1 = (const float*)d_in[1];
    int* out = (int*)d_out;
    char* ws = (char*)d_ws;

    // ws layout (bytes)
    float* Kd      = (float*)(ws + 0ull);                 // 134217728
    float* partial = (float*)(ws + 134217728ull);         // 8388608
    float* u       = (float*)(ws + 142606336ull);         // 65536
    float* v       = (float*)(ws + 142671872ull);         // 65536
    float* sq0     = (float*)(ws + 142737408ull);         // 65536
    float* sq1     = (float*)(ws + 142802944ull);         // 65536
    unsigned* maxd = (unsigned*)(ws + 142868480ull);      // 32

    init_k<<<64, 256, 0, stream>>>(v, maxd);
    sq_k<<<8192, 256, 0, stream>>>(x0, x1, sq0, sq1);
    distc_k<0><<<4096, 256, 0, stream>>>(x0, x1, sq0, sq1, Kd, maxd);  // max(d2) per batch
    distc_k<1><<<4096, 256, 0, stream>>>(x0, x1, sq0, sq1, Kd, maxd);  // K = exp(-d/..)
    for (int it = 0; it < NUM_ITERS; ++it) {
        sink_k<<<1024, 512, 0, stream>>>(Kd, v, u, partial);
        vred_k<<<64, 256, 0, stream>>>(partial, v);
    }
    argmax_k<<<4096, 256, 0, stream>>>(Kd, u, v, out);
}